// Round 1
// baseline (43720.325 us; speedup 1.0000x reference)
//
#include <hip/hip_runtime.h>
#include <math.h>

#define DIM 512
#define NSLOTS 32
#define BATCH 32
#define SEQT 2048

// ============================================================================
// Kernel 1: X[m,o] = sum_k x_seq[m,k] * W_x[o,k] + b_h[o]
// written into d_out's h_seq region (consumed in-place, then overwritten, by
// the recurrent kernel). M = B*T = 65536, N = K = 512.
// Classic 64x64 tile, 256 threads, 4x4 micro-tile, K-tiles of 16.
// ============================================================================
__global__ __launch_bounds__(256) void xw_gemm_kernel(
    const float* __restrict__ A,    // x_seq [M, 512]
    const float* __restrict__ Bm,   // W_x   [512, 512] row-major (out, in)
    const float* __restrict__ bias, // b_h [512]
    float* __restrict__ C)          // [M, 512]
{
    // K-major staging, transposed into [k][row] so the inner loop does
    // broadcast/2-way-free float4 LDS reads. Row stride 68 keeps 16B align.
    __shared__ __align__(16) float As[16][68];
    __shared__ __align__(16) float Bs[16][68];

    const int tid = threadIdx.x;
    const int tx = tid & 15, ty = tid >> 4;
    const int bm = blockIdx.x, bo = blockIdx.y;
    const int r = tid >> 2, c = tid & 3;

    float acc[4][4];
#pragma unroll
    for (int i = 0; i < 4; ++i)
#pragma unroll
        for (int j = 0; j < 4; ++j) acc[i][j] = 0.f;

    const float* Arow = A + (size_t)(bm * 64 + r) * DIM + c * 4;
    const float* Brow = Bm + (size_t)(bo * 64 + r) * DIM + c * 4;

    for (int kt = 0; kt < DIM / 16; ++kt) {
        float4 a4 = *(const float4*)(Arow + kt * 16);
        float4 b4 = *(const float4*)(Brow + kt * 16);
        As[c * 4 + 0][r] = a4.x; As[c * 4 + 1][r] = a4.y;
        As[c * 4 + 2][r] = a4.z; As[c * 4 + 3][r] = a4.w;
        Bs[c * 4 + 0][r] = b4.x; Bs[c * 4 + 1][r] = b4.y;
        Bs[c * 4 + 2][r] = b4.z; Bs[c * 4 + 3][r] = b4.w;
        __syncthreads();
#pragma unroll
        for (int kk = 0; kk < 16; ++kk) {
            float4 av = *(const float4*)&As[kk][ty * 4];
            float4 bv = *(const float4*)&Bs[kk][tx * 4];
            float a[4] = {av.x, av.y, av.z, av.w};
            float b[4] = {bv.x, bv.y, bv.z, bv.w};
#pragma unroll
            for (int i = 0; i < 4; ++i)
#pragma unroll
                for (int j = 0; j < 4; ++j)
                    acc[i][j] = fmaf(a[i], b[j], acc[i][j]);
        }
        __syncthreads();
    }

    const int col = bo * 64 + tx * 4;
    float4 bia = *(const float4*)(bias + col);
#pragma unroll
    for (int i = 0; i < 4; ++i) {
        float4 v = {acc[i][0] + bia.x, acc[i][1] + bia.y,
                    acc[i][2] + bia.z, acc[i][3] + bia.w};
        *(float4*)(C + (size_t)(bm * 64 + ty * 4 + i) * DIM + col) = v;
    }
}

// ============================================================================
// Entmax-1.5 over 32 slots, exact sort-based algorithm (matches reference).
// Done by the first 32 lanes (wave 0). scores -> pout. Uses zs as scratch.
// ============================================================================
__device__ __forceinline__ void entmax_block(const float* __restrict__ sc,
                                             float* __restrict__ zs,
                                             float* __restrict__ pout,
                                             int tid)
{
    float z = 0.f;
    if (tid < 32) {
        z = sc[tid] * 0.5f;
        float zmax = z;
#pragma unroll
        for (int off = 16; off >= 1; off >>= 1)
            zmax = fmaxf(zmax, __shfl_xor(zmax, off, 32));
        z -= zmax;
        // rank (stable under ties) -> scatter gives descending sort
        int rank = 0;
        for (int j = 0; j < 32; ++j) {
            float zj = __shfl(z, j, 32);
            rank += (zj > z) || (zj == z && j < tid);
        }
        zs[rank] = z;
    }
    __syncthreads();
    if (tid < 32) {
        float zsv = zs[tid];
        float cs = zsv, css = zsv * zsv;
        // inclusive scan across 32 lanes
#pragma unroll
        for (int off = 1; off < 32; off <<= 1) {
            float a = __shfl_up(cs, off, 32);
            float b2 = __shfl_up(css, off, 32);
            if (tid >= off) { cs += a; css += b2; }
        }
        float k = (float)(tid + 1);
        float mean = cs / k;
        float meansq = css / k;
        float ss = k * (meansq - mean * mean);
        float delta = fmaxf((1.0f - ss) / k, 0.0f);
        float tau = mean - sqrtf(delta);
        unsigned long long ball = __ballot(tau <= zsv);
        int kstar = __popcll(ball) - 1;
        float taustar = __shfl(tau, kstar, 32);
        float pp = fmaxf(z - taustar, 0.0f);
        pout[tid] = pp * pp;
    }
    __syncthreads();
}

// ============================================================================
// matvec: vout[o] = dot(W[o,:], vin) (+ xr[o] + rd[o], tanh) for o in [0,512)
// 512 threads: 16 lanes per output, 32 outputs per pass, 16 passes.
// Lane reads are float4, 64B-contiguous per 16-lane group (coalesced).
// ============================================================================
template <bool DO_TANH>
__device__ __forceinline__ void matvec512(const float* __restrict__ W,
                                          const float* __restrict__ vin,
                                          float* __restrict__ vout,
                                          const float* __restrict__ xr,
                                          const float* __restrict__ rd,
                                          int tid)
{
    const int grp = tid >> 4, l16 = tid & 15;
#pragma unroll 2
    for (int p = 0; p < 16; ++p) {
        const int o = p * 32 + grp;
        const float* Wrow = W + (size_t)o * DIM;
        float acc = 0.f;
#pragma unroll
        for (int j = 0; j < 8; ++j) {
            float4 w4 = *(const float4*)(Wrow + l16 * 4 + 64 * j);
            float4 v4 = *(const float4*)(vin + l16 * 4 + 64 * j);
            acc = fmaf(w4.x, v4.x, acc);
            acc = fmaf(w4.y, v4.y, acc);
            acc = fmaf(w4.z, v4.z, acc);
            acc = fmaf(w4.w, v4.w, acc);
        }
#pragma unroll
        for (int off = 8; off >= 1; off >>= 1)
            acc += __shfl_down(acc, off, 16);
        if (l16 == 0) {
            if (DO_TANH)
                vout[o] = tanhf(acc + xr[o] + rd[o]);
            else
                vout[o] = acc;
        }
    }
}

// ============================================================================
// Kernel 2: fused recurrence. One workgroup per batch element (no inter-WG
// communication needed — batches are independent). Tape + all per-step
// vectors live in LDS (~74 KB < 160 KB gfx950 LDS).
// ============================================================================
__global__ __launch_bounds__(512) void recurrent_kernel(
    const float* __restrict__ h_tape0,
    const float* __restrict__ h_work0,
    const float* __restrict__ W_h,
    const float* __restrict__ W_write,
    float* __restrict__ out)
{
    __shared__ __align__(16) float tape[NSLOTS][DIM];   // 64 KB
    __shared__ __align__(16) float work[DIM];
    __shared__ __align__(16) float worknew[DIM];
    __shared__ __align__(16) float wvec[DIM];
    __shared__ __align__(16) float readv[DIM];
    __shared__ __align__(16) float xrow[DIM];
    __shared__ float scores[NSLOTS];
    __shared__ float zsort[NSLOTS];
    __shared__ float prob[NSLOTS];

    const int tid = threadIdx.x;
    const int b = blockIdx.x;
    const float inv_sqrt_d = 0.044194173824159216f;  // 1/sqrt(512)

    for (int i = tid; i < NSLOTS * DIM; i += 512)
        ((float*)tape)[i] = h_tape0[(size_t)b * NSLOTS * DIM + i];
    work[tid] = h_work0[b * DIM + tid];
    __syncthreads();

    float* hseq_b = out + (size_t)b * SEQT * DIM;
    const int grp = tid >> 4, l16 = tid & 15;

    for (int t = 0; t < SEQT; ++t) {
        // stage precomputed X row (from d_out, in-place) + read scores
        xrow[tid] = hseq_b[(size_t)t * DIM + tid];
        {
            float p = 0.f;
#pragma unroll 8
            for (int j = 0; j < 32; ++j)
                p = fmaf(tape[grp][l16 + 16 * j], work[l16 + 16 * j], p);
#pragma unroll
            for (int off = 8; off >= 1; off >>= 1)
                p += __shfl_down(p, off, 16);
            if (l16 == 0) scores[grp] = p * inv_sqrt_d;
        }
        __syncthreads();

        entmax_block(scores, zsort, prob, tid);  // prob = alpha

        // read vector
        {
            float rv = 0.f;
#pragma unroll
            for (int n = 0; n < NSLOTS; ++n)
                rv = fmaf(prob[n], tape[n][tid], rv);
            readv[tid] = rv;
        }
        __syncthreads();

        // work_new = tanh(W_h @ work + X + read)
        matvec512<true>(W_h, work, worknew, xrow, readv, tid);
        __syncthreads();

        // w_vec = W_write @ work_new
        matvec512<false>(W_write, worknew, wvec, nullptr, nullptr, tid);
        __syncthreads();

        // write scores
        {
            float p = 0.f;
#pragma unroll 8
            for (int j = 0; j < 32; ++j)
                p = fmaf(tape[grp][l16 + 16 * j], wvec[l16 + 16 * j], p);
#pragma unroll
            for (int off = 8; off >= 1; off >>= 1)
                p += __shfl_down(p, off, 16);
            if (l16 == 0) scores[grp] = p * inv_sqrt_d;
        }
        __syncthreads();

        entmax_block(scores, zsort, prob, tid);  // prob = beta

        // tape update, h_seq write, work <- work_new
        {
            float wv = wvec[tid];
#pragma unroll
            for (int n = 0; n < NSLOTS; ++n) {
                float bb = prob[n];
                float tv = tape[n][tid];
                tape[n][tid] = tv * (1.0f - bb) + bb * wv;
            }
            float wn = worknew[tid];
            work[tid] = wn;
            hseq_b[(size_t)t * DIM + tid] = wn;
        }
        __syncthreads();
    }

    // epilogue: tape_final and h_last
    for (int i = tid; i < NSLOTS * DIM; i += 512)
        out[(size_t)BATCH * SEQT * DIM + (size_t)b * NSLOTS * DIM + i] =
            ((float*)tape)[i];
    out[(size_t)BATCH * SEQT * DIM + (size_t)BATCH * NSLOTS * DIM +
        (size_t)b * DIM + tid] = work[tid];
}

// ============================================================================
extern "C" void kernel_launch(void* const* d_in, const int* in_sizes, int n_in,
                              void* d_out, int out_size, void* d_ws,
                              size_t ws_size, hipStream_t stream)
{
    const float* x_seq   = (const float*)d_in[0];
    const float* h_tape  = (const float*)d_in[1];
    const float* h_work  = (const float*)d_in[2];
    const float* W_h     = (const float*)d_in[3];
    const float* W_x     = (const float*)d_in[4];
    const float* b_h     = (const float*)d_in[5];
    const float* W_write = (const float*)d_in[6];
    float* out = (float*)d_out;

    // Phase 1: X = x_seq @ W_x^T + b_h, staged into out's h_seq region.
    dim3 g1((BATCH * SEQT) / 64, DIM / 64);
    xw_gemm_kernel<<<g1, 256, 0, stream>>>(x_seq, W_x, b_h, out);

    // Phase 2: fused recurrence, one WG per batch.
    recurrent_kernel<<<BATCH, 512, 0, stream>>>(h_tape, h_work, W_h, W_write,
                                                out);
}

// Round 2
// 25809.637 us; speedup vs baseline: 1.6940x; 1.6940x over previous
//
#include <hip/hip_runtime.h>
#include <math.h>

#define DIM 512
#define NSLOTS 32
#define BATCH 32
#define SEQT 2048
#define KSPLIT 8
#define SLICE 64  // DIM / KSPLIT

#define SCOPE_AGENT __HIP_MEMORY_SCOPE_AGENT

// ============================================================================
// Kernel 1: X[m,o] = sum_k x_seq[m,k] * W_x[o,k] + b_h[o]
// written into d_out's h_seq region (consumed in-place, then overwritten, by
// the recurrent kernel). M = B*T = 65536, N = K = 512.
// ============================================================================
__global__ __launch_bounds__(256) void xw_gemm_kernel(
    const float* __restrict__ A,    // x_seq [M, 512]
    const float* __restrict__ Bm,   // W_x   [512, 512] row-major (out, in)
    const float* __restrict__ bias, // b_h [512]
    float* __restrict__ C)          // [M, 512]
{
    __shared__ __align__(16) float As[16][68];
    __shared__ __align__(16) float Bs[16][68];

    const int tid = threadIdx.x;
    const int tx = tid & 15, ty = tid >> 4;
    const int bm = blockIdx.x, bo = blockIdx.y;
    const int r = tid >> 2, c = tid & 3;

    float acc[4][4];
#pragma unroll
    for (int i = 0; i < 4; ++i)
#pragma unroll
        for (int j = 0; j < 4; ++j) acc[i][j] = 0.f;

    const float* Arow = A + (size_t)(bm * 64 + r) * DIM + c * 4;
    const float* Brow = Bm + (size_t)(bo * 64 + r) * DIM + c * 4;

    for (int kt = 0; kt < DIM / 16; ++kt) {
        float4 a4 = *(const float4*)(Arow + kt * 16);
        float4 b4 = *(const float4*)(Brow + kt * 16);
        As[c * 4 + 0][r] = a4.x; As[c * 4 + 1][r] = a4.y;
        As[c * 4 + 2][r] = a4.z; As[c * 4 + 3][r] = a4.w;
        Bs[c * 4 + 0][r] = b4.x; Bs[c * 4 + 1][r] = b4.y;
        Bs[c * 4 + 2][r] = b4.z; Bs[c * 4 + 3][r] = b4.w;
        __syncthreads();
#pragma unroll
        for (int kk = 0; kk < 16; ++kk) {
            float4 av = *(const float4*)&As[kk][ty * 4];
            float4 bv = *(const float4*)&Bs[kk][tx * 4];
            float a[4] = {av.x, av.y, av.z, av.w};
            float b[4] = {bv.x, bv.y, bv.z, bv.w};
#pragma unroll
            for (int i = 0; i < 4; ++i)
#pragma unroll
                for (int j = 0; j < 4; ++j)
                    acc[i][j] = fmaf(a[i], b[j], acc[i][j]);
        }
        __syncthreads();
    }

    const int col = bo * 64 + tx * 4;
    float4 bia = *(const float4*)(bias + col);
#pragma unroll
    for (int i = 0; i < 4; ++i) {
        float4 v = {acc[i][0] + bia.x, acc[i][1] + bia.y,
                    acc[i][2] + bia.z, acc[i][3] + bia.w};
        *(float4*)(C + (size_t)(bm * 64 + ty * 4 + i) * DIM + col) = v;
    }
}

// ============================================================================
// Entmax-1.5 over 32 slots (exact sort-based, matches reference).
// ============================================================================
__device__ __forceinline__ void entmax_block(const float* __restrict__ sc,
                                             float* __restrict__ zs,
                                             float* __restrict__ pout,
                                             int tid)
{
    float z = 0.f;
    if (tid < 32) {
        z = sc[tid] * 0.5f;
        float zmax = z;
#pragma unroll
        for (int off = 16; off >= 1; off >>= 1)
            zmax = fmaxf(zmax, __shfl_xor(zmax, off, 32));
        z -= zmax;
        int rank = 0;
        for (int j = 0; j < 32; ++j) {
            float zj = __shfl(z, j, 32);
            rank += (zj > z) || (zj == z && j < tid);
        }
        zs[rank] = z;
    }
    __syncthreads();
    if (tid < 32) {
        float zsv = zs[tid];
        float cs = zsv, css = zsv * zsv;
#pragma unroll
        for (int off = 1; off < 32; off <<= 1) {
            float a = __shfl_up(cs, off, 32);
            float b2 = __shfl_up(css, off, 32);
            if (tid >= off) { cs += a; css += b2; }
        }
        float k = (float)(tid + 1);
        float mean = cs / k;
        float meansq = css / k;
        float ss = k * (meansq - mean * mean);
        float delta = fmaxf((1.0f - ss) / k, 0.0f);
        float tau = mean - sqrtf(delta);
        unsigned long long ball = __ballot(tau <= zsv);
        int kstar = __popcll(ball) - 1;
        float taustar = __shfl(tau, kstar, 32);
        float pp = fmaxf(z - taustar, 0.0f);
        pout[tid] = pp * pp;
    }
    __syncthreads();
}

// ============================================================================
// Kernel 2: fused recurrence, KSPLIT=8 WGs per batch (256 WGs total).
// WG (b,k) owns output rows [k*64,(k+1)*64) of both matvecs; per-step weight
// stream drops from 2 MB to 256 KB per CU. Small phases (scores, entmax,
// readv, tape update) are duplicated bitwise-identically in all 8 WGs, so the
// only cross-WG traffic is the work_new / w_vec slice exchange.
//
// Exchange protocol (agent-scope RELAXED atomics only — acquire/release would
// emit buffer_inv and evict the L2-resident weights):
//   producer: atomic-store slice -> s_waitcnt vmcnt(0) -> syncthreads ->
//             lane0 fetch_add(cnt) ; consumer: spin cnt >= (t+1)*K ->
//             syncthreads -> atomic-load full vector.
// Overwrite safety: a WG writes wn_x at t+1 only after passing spinB(t),
// which implies every WG did addB(t), which is program-ordered after its read
// of wn_x(t). Similarly wv_x writes at t+1 are gated by spinA(t+1) which is
// ordered after every WG's read of wv_x(t).
// k = blockIdx&7: under round-robin block->XCD placement, same-k WGs share an
// XCD so each XCD L2 holds only one 512 KB weight slice pair (perf-only).
// ============================================================================
__global__ __launch_bounds__(512) void recurrent_kernel(
    const float* __restrict__ h_tape0,
    const float* __restrict__ h_work0,
    const float* __restrict__ W_h,
    const float* __restrict__ W_write,
    float* out,
    float* wn_x,              // [BATCH][DIM] exchange buffer
    float* wv_x,              // [BATCH][DIM] exchange buffer
    int* cnt)                 // [BATCH][64]: [b][0]=cntA, [b][32]=cntB
{
    __shared__ __align__(16) float tape[NSLOTS][DIM];   // 64 KB
    __shared__ __align__(16) float work[DIM];
    __shared__ __align__(16) float worknew[DIM];
    __shared__ __align__(16) float wvec[DIM];
    __shared__ __align__(16) float readv[DIM];
    __shared__ __align__(16) float xsl[SLICE];
    __shared__ float scores[NSLOTS];
    __shared__ float zsort[NSLOTS];
    __shared__ float prob[NSLOTS];
    __shared__ int deadflag;

    const int tid = threadIdx.x;
    const int bid = blockIdx.x;
    const int k = bid & 7;
    const int b = bid >> 3;
    const float inv_sqrt_d = 0.044194173824159216f;  // 1/sqrt(512)

    if (tid == 0) deadflag = 0;
    for (int i = tid; i < NSLOTS * DIM; i += 512)
        ((float*)tape)[i] = h_tape0[(size_t)b * NSLOTS * DIM + i];
    work[tid] = h_work0[b * DIM + tid];
    __syncthreads();

    float* hseq_b = out + (size_t)b * SEQT * DIM;
    const int grp = tid >> 4, l16 = tid & 15;
    int* cntA = cnt + b * 64;
    int* cntB = cnt + b * 64 + 32;
    float* wn_b = wn_x + b * DIM;
    float* wv_b = wv_x + b * DIM;

    for (int t = 0; t < SEQT; ++t) {
        // x slice for this WG's rows + read scores (local, duplicated)
        if (tid < SLICE) xsl[tid] = hseq_b[(size_t)t * DIM + k * SLICE + tid];
        {
            float p = 0.f;
#pragma unroll 8
            for (int j = 0; j < 32; ++j)
                p = fmaf(tape[grp][l16 + 16 * j], work[l16 + 16 * j], p);
#pragma unroll
            for (int off = 8; off >= 1; off >>= 1)
                p += __shfl_down(p, off, 16);
            if (l16 == 0) scores[grp] = p * inv_sqrt_d;
        }
        __syncthreads();

        entmax_block(scores, zsort, prob, tid);  // prob = alpha

        {
            float rv = 0.f;
#pragma unroll
            for (int n = 0; n < NSLOTS; ++n)
                rv = fmaf(prob[n], tape[n][tid], rv);
            readv[tid] = rv;
        }
        __syncthreads();

        // matvec1 slice: worknew rows [k*64, k*64+64)
#pragma unroll
        for (int p = 0; p < 2; ++p) {
            const int r = p * 32 + grp;
            const int o = k * SLICE + r;
            const float* Wrow = W_h + (size_t)o * DIM;
            float acc = 0.f;
#pragma unroll
            for (int j = 0; j < 8; ++j) {
                float4 w4 = *(const float4*)(Wrow + l16 * 4 + 64 * j);
                float4 v4 = *(const float4*)(work + l16 * 4 + 64 * j);
                acc = fmaf(w4.x, v4.x, acc);
                acc = fmaf(w4.y, v4.y, acc);
                acc = fmaf(w4.z, v4.z, acc);
                acc = fmaf(w4.w, v4.w, acc);
            }
#pragma unroll
            for (int off = 8; off >= 1; off >>= 1)
                acc += __shfl_down(acc, off, 16);
            if (l16 == 0) {
                float val = tanhf(acc + xsl[r] + readv[o]);
                __hip_atomic_store(&wn_b[o], val, __ATOMIC_RELAXED, SCOPE_AGENT);
            }
        }
        asm volatile("s_waitcnt vmcnt(0)" ::: "memory");
        __syncthreads();
        if (tid == 0 && !deadflag) {
            __hip_atomic_fetch_add(cntA, 1, __ATOMIC_RELAXED, SCOPE_AGENT);
            const int target = (t + 1) * KSPLIT;
            int it = 0;
            while (__hip_atomic_load(cntA, __ATOMIC_RELAXED, SCOPE_AGENT) < target) {
                __builtin_amdgcn_s_sleep(2);
                if (++it > (1 << 20)) { deadflag = 1; break; }
            }
        }
        __syncthreads();
        worknew[tid] = __hip_atomic_load(&wn_b[tid], __ATOMIC_RELAXED, SCOPE_AGENT);
        __syncthreads();

        // matvec2 slice: wvec rows [k*64, k*64+64)
#pragma unroll
        for (int p = 0; p < 2; ++p) {
            const int r = p * 32 + grp;
            const int o = k * SLICE + r;
            const float* Wrow = W_write + (size_t)o * DIM;
            float acc = 0.f;
#pragma unroll
            for (int j = 0; j < 8; ++j) {
                float4 w4 = *(const float4*)(Wrow + l16 * 4 + 64 * j);
                float4 v4 = *(const float4*)(worknew + l16 * 4 + 64 * j);
                acc = fmaf(w4.x, v4.x, acc);
                acc = fmaf(w4.y, v4.y, acc);
                acc = fmaf(w4.z, v4.z, acc);
                acc = fmaf(w4.w, v4.w, acc);
            }
#pragma unroll
            for (int off = 8; off >= 1; off >>= 1)
                acc += __shfl_down(acc, off, 16);
            if (l16 == 0)
                __hip_atomic_store(&wv_b[o], acc, __ATOMIC_RELAXED, SCOPE_AGENT);
        }
        asm volatile("s_waitcnt vmcnt(0)" ::: "memory");
        __syncthreads();
        if (tid == 0 && !deadflag) {
            __hip_atomic_fetch_add(cntB, 1, __ATOMIC_RELAXED, SCOPE_AGENT);
            const int target = (t + 1) * KSPLIT;
            int it = 0;
            while (__hip_atomic_load(cntB, __ATOMIC_RELAXED, SCOPE_AGENT) < target) {
                __builtin_amdgcn_s_sleep(2);
                if (++it > (1 << 20)) { deadflag = 1; break; }
            }
        }
        __syncthreads();
        wvec[tid] = __hip_atomic_load(&wv_b[tid], __ATOMIC_RELAXED, SCOPE_AGENT);
        __syncthreads();

        // write scores (local, duplicated)
        {
            float p = 0.f;
#pragma unroll 8
            for (int j = 0; j < 32; ++j)
                p = fmaf(tape[grp][l16 + 16 * j], wvec[l16 + 16 * j], p);
#pragma unroll
            for (int off = 8; off >= 1; off >>= 1)
                p += __shfl_down(p, off, 16);
            if (l16 == 0) scores[grp] = p * inv_sqrt_d;
        }
        __syncthreads();

        entmax_block(scores, zsort, prob, tid);  // prob = beta

        // tape update (duplicated, bitwise identical), h_seq slice, work swap
        {
            float wv = wvec[tid];
#pragma unroll
            for (int n = 0; n < NSLOTS; ++n) {
                float bb = prob[n];
                float tv = tape[n][tid];
                tape[n][tid] = tv * (1.0f - bb) + bb * wv;
            }
            work[tid] = worknew[tid];
        }
        if (tid < SLICE)
            hseq_b[(size_t)t * DIM + k * SLICE + tid] = worknew[k * SLICE + tid];
        __syncthreads();
    }

    // epilogue: WG k writes tape slots [k*4,(k+1)*4) and its h_last slice
    const size_t tape_off = (size_t)BATCH * SEQT * DIM + (size_t)b * NSLOTS * DIM;
    for (int i = tid; i < 4 * DIM; i += 512)
        out[tape_off + (size_t)k * 4 * DIM + i] = ((float*)tape)[k * 4 * DIM + i];
    if (tid < SLICE)
        out[(size_t)BATCH * SEQT * DIM + (size_t)BATCH * NSLOTS * DIM +
            (size_t)b * DIM + k * SLICE + tid] = work[k * SLICE + tid];
}

// ============================================================================
extern "C" void kernel_launch(void* const* d_in, const int* in_sizes, int n_in,
                              void* d_out, int out_size, void* d_ws,
                              size_t ws_size, hipStream_t stream)
{
    const float* x_seq   = (const float*)d_in[0];
    const float* h_tape  = (const float*)d_in[1];
    const float* h_work  = (const float*)d_in[2];
    const float* W_h     = (const float*)d_in[3];
    const float* W_x     = (const float*)d_in[4];
    const float* b_h     = (const float*)d_in[5];
    const float* W_write = (const float*)d_in[6];
    float* out = (float*)d_out;

    float* wn_x = (float*)d_ws;
    float* wv_x = wn_x + BATCH * DIM;
    int* cnt = (int*)((char*)d_ws + (size_t)2 * BATCH * DIM * 4);

    // counters must start at 0 every launch (d_ws is re-poisoned to 0xAA)
    hipMemsetAsync(cnt, 0, BATCH * 64 * sizeof(int), stream);

    dim3 g1((BATCH * SEQT) / 64, DIM / 64);
    xw_gemm_kernel<<<g1, 256, 0, stream>>>(x_seq, W_x, b_h, out);

    recurrent_kernel<<<BATCH * KSPLIT, 512, 0, stream>>>(
        h_tape, h_work, W_h, W_write, out, wn_x, wv_x, cnt);
}

// Round 3
// 22887.967 us; speedup vs baseline: 1.9102x; 1.1277x over previous
//
#include <hip/hip_runtime.h>
#include <math.h>

#define DIM 512
#define NSLOTS 32
#define BATCH 32
#define SEQT 2048
#define KSPLIT 8
#define SLICE 64   // DIM / KSPLIT
#define TPB 576    // 9 waves: waves 0-7 stream weights, wave 8 does serial small phases

#define SCOPE_AGENT __HIP_MEMORY_SCOPE_AGENT

// ============================================================================
// Kernel 0: transpose W_write (512x512) -> Wwt[c][o] = W_write[o][c]
// so the column-sliced matvec2 streams coalesced rows.
// ============================================================================
__global__ __launch_bounds__(256) void transpose512_kernel(
    const float* __restrict__ W, float* __restrict__ Wt)
{
    __shared__ float tile[32][33];
    const int tx = threadIdx.x, ty = threadIdx.y;  // 32 x 8
    const int x = blockIdx.x * 32 + tx;
    const int y0 = blockIdx.y * 32;
#pragma unroll
    for (int j = 0; j < 4; ++j)
        tile[ty + 8 * j][tx] = W[(size_t)(y0 + ty + 8 * j) * DIM + x];
    __syncthreads();
    const int x2 = blockIdx.y * 32 + tx;
    const int y2 = blockIdx.x * 32;
#pragma unroll
    for (int j = 0; j < 4; ++j)
        Wt[(size_t)(y2 + ty + 8 * j) * DIM + x2] = tile[tx][ty + 8 * j];
}

// ============================================================================
// Kernel 1: X[m,o] = sum_k x_seq[m,k] * W_x[o,k] + b_h[o]  (into d_out h_seq)
// ============================================================================
__global__ __launch_bounds__(256) void xw_gemm_kernel(
    const float* __restrict__ A,    // x_seq [M, 512]
    const float* __restrict__ Bm,   // W_x   [512, 512]
    const float* __restrict__ bias, // b_h [512]
    float* __restrict__ C)          // [M, 512]
{
    __shared__ __align__(16) float As[16][68];
    __shared__ __align__(16) float Bs[16][68];

    const int tid = threadIdx.x;
    const int tx = tid & 15, ty = tid >> 4;
    const int bm = blockIdx.x, bo = blockIdx.y;
    const int r = tid >> 2, c = tid & 3;

    float acc[4][4];
#pragma unroll
    for (int i = 0; i < 4; ++i)
#pragma unroll
        for (int j = 0; j < 4; ++j) acc[i][j] = 0.f;

    const float* Arow = A + (size_t)(bm * 64 + r) * DIM + c * 4;
    const float* Brow = Bm + (size_t)(bo * 64 + r) * DIM + c * 4;

    for (int kt = 0; kt < DIM / 16; ++kt) {
        float4 a4 = *(const float4*)(Arow + kt * 16);
        float4 b4 = *(const float4*)(Brow + kt * 16);
        As[c * 4 + 0][r] = a4.x; As[c * 4 + 1][r] = a4.y;
        As[c * 4 + 2][r] = a4.z; As[c * 4 + 3][r] = a4.w;
        Bs[c * 4 + 0][r] = b4.x; Bs[c * 4 + 1][r] = b4.y;
        Bs[c * 4 + 2][r] = b4.z; Bs[c * 4 + 3][r] = b4.w;
        __syncthreads();
#pragma unroll
        for (int kk = 0; kk < 16; ++kk) {
            float4 av = *(const float4*)&As[kk][ty * 4];
            float4 bv = *(const float4*)&Bs[kk][tx * 4];
            float a[4] = {av.x, av.y, av.z, av.w};
            float b[4] = {bv.x, bv.y, bv.z, bv.w};
#pragma unroll
            for (int i = 0; i < 4; ++i)
#pragma unroll
                for (int j = 0; j < 4; ++j)
                    acc[i][j] = fmaf(a[i], b[j], acc[i][j]);
        }
        __syncthreads();
    }

    const int col = bo * 64 + tx * 4;
    float4 bia = *(const float4*)(bias + col);
#pragma unroll
    for (int i = 0; i < 4; ++i) {
        float4 v = {acc[i][0] + bia.x, acc[i][1] + bia.y,
                    acc[i][2] + bia.z, acc[i][3] + bia.w};
        *(float4*)(C + (size_t)(bm * 64 + ty * 4 + i) * DIM + col) = v;
    }
}

// ============================================================================
// Entmax-1.5 over 32 slots, fully in-wave (no LDS, no barriers).
// Caller must invoke under `if (lane < 32)`; `sc` = score for slot == lane.
// Sort scatter uses ds_permute (push to lane `rank`), exact same math as the
// sort-based reference.
// ============================================================================
__device__ __forceinline__ float entmax_wave(float sc, int lane)
{
    float z = sc * 0.5f;
    float zmax = z;
#pragma unroll
    for (int off = 16; off >= 1; off >>= 1)
        zmax = fmaxf(zmax, __shfl_xor(zmax, off, 32));
    z -= zmax;
    int rank = 0;
#pragma unroll
    for (int j = 0; j < 32; ++j) {
        float zj = __shfl(z, j, 32);
        rank += (zj > z) || (zj == z && j < lane);
    }
    // zs[rank] = z scatter, in-register: push z to lane `rank`
    float zsv = __int_as_float(
        __builtin_amdgcn_ds_permute(rank << 2, __float_as_int(z)));
    float cs = zsv, css = zsv * zsv;
#pragma unroll
    for (int off = 1; off < 32; off <<= 1) {
        float a = __shfl_up(cs, off, 32);
        float b2 = __shfl_up(css, off, 32);
        if (lane >= off) { cs += a; css += b2; }
    }
    float kk = (float)(lane + 1);
    float mean = cs / kk, meansq = css / kk;
    float ss = kk * (meansq - mean * mean);
    float delta = fmaxf((1.0f - ss) / kk, 0.0f);
    float tau = mean - sqrtf(delta);
    unsigned long long ball = __ballot(tau <= zsv);
    int kstar = __popcll(ball & 0xFFFFFFFFull) - 1;
    float taustar = __shfl(tau, kstar, 32);
    float pp = fmaxf(z - taustar, 0.0f);
    return pp * pp;
}

// ============================================================================
// Kernel 2: fused recurrence. 8 WGs per batch; ONE cross-WG sync per step.
//  - waves 0-7 (512 thr): stream W_h slice (row-split matvec1) in parallel
//    with wave 8 doing read-scores -> entmax -> readv-slice.
//  - matvec2 is COLUMN-sliced (uses only the local work_new slice, via the
//    pre-transposed Wwt) so it needs no exchange; partials are summed by
//    every WG in a fixed order after the single counter sync (bitwise
//    deterministic -> all WGs keep identical tape/work state).
//  - wn/parts are parity double-buffered: writes to buffer p at step t+2 are
//    gated by sync(t+1), which is program-ordered after every WG's reads of
//    buffer p at step t.  Agent-scope relaxed atomics only (no L2-flushing
//    fences); s_waitcnt vmcnt(0) orders stores before the counter add.
// ============================================================================
__global__ __launch_bounds__(TPB) void recurrent_kernel(
    const float* __restrict__ h_tape0,
    const float* __restrict__ h_work0,
    const float* __restrict__ W_h,
    const float* __restrict__ Wwt,   // W_write transposed [c][o]
    float* out,
    float* wn_x,    // [2][BATCH][DIM]
    float* parts,   // [2][BATCH][KSPLIT][DIM]
    int* cnt)       // [BATCH][32]
{
    __shared__ __align__(16) float tape[NSLOTS][DIM];   // 64 KB
    __shared__ __align__(16) float work[DIM];
    __shared__ __align__(16) float wvec[DIM];
    __shared__ float wnsl[SLICE];
    __shared__ float xsl[SLICE];
    __shared__ float rdsl[SLICE];
    __shared__ float scores[NSLOTS];
    __shared__ float prob[NSLOTS];
    __shared__ int deadflag;

    const int tid = threadIdx.x;
    const int bid = blockIdx.x;
    const int k = bid & 7;          // slice id (XCD-affine under round-robin)
    const int b = bid >> 3;
    const float inv_sqrt_d = 0.044194173824159216f;  // 1/sqrt(512)

    if (tid == 0) deadflag = 0;
    for (int i = tid; i < NSLOTS * DIM; i += TPB)
        ((float*)tape)[i] = h_tape0[(size_t)b * NSLOTS * DIM + i];
    if (tid < DIM) work[tid] = h_work0[b * DIM + tid];
    __syncthreads();

    float* hseq_b = out + (size_t)b * SEQT * DIM;
    int* cnt_b = cnt + b * 32;

    for (int t = 0; t < SEQT; ++t) {
        const int pbuf = t & 1;
        float* wnb = wn_x + pbuf * (BATCH * DIM) + b * DIM;
        float* pb = parts + pbuf * (BATCH * KSPLIT * DIM) + b * KSPLIT * DIM;

        float mv1 = 0.f;  // matvec1 partial (threads 0-511)
        if (tid >= 512) {
            // ---------------- wave 8: serial small phases ----------------
            const int lw = tid - 512;           // 0..63
            // prefetch x slice for this WG's rows (consumed after JOIN1)
            float xv = hseq_b[(size_t)t * DIM + k * SLICE + lw];

            // read scores: 2 lanes per slot, float4, slot-rotated banks
            const int s = lw >> 1, l2 = lw & 1;
            const float4* tp4 = (const float4*)&tape[s][0];
            const float4* wk4 = (const float4*)work;
            float4 a4 = {0.f, 0.f, 0.f, 0.f};
#pragma unroll 8
            for (int j = 0; j < 64; ++j) {
                int f = (l2 + 2 * (j + s)) & 127;
                float4 tv = tp4[f];
                float4 wv = wk4[f];
                a4.x = fmaf(tv.x, wv.x, a4.x);
                a4.y = fmaf(tv.y, wv.y, a4.y);
                a4.z = fmaf(tv.z, wv.z, a4.z);
                a4.w = fmaf(tv.w, wv.w, a4.w);
            }
            float p = (a4.x + a4.y) + (a4.z + a4.w);
            p += __shfl_xor(p, 1, 64);
            p *= inv_sqrt_d;
            // repack: lane i (<32) gets slot i's score (from lane 2i)
            float psl = __shfl(p, (lw & 31) << 1, 64);
            float alpha = 0.f;
            if (lw < 32) alpha = entmax_wave(psl, lw);

            // readv slice: rdsl[lw] = sum_n alpha[n] * tape[n][k*64+lw]
            float racc = 0.f;
#pragma unroll
            for (int n = 0; n < NSLOTS; ++n) {
                float pn = __shfl(alpha, n, 64);
                racc = fmaf(pn, tape[n][k * SLICE + lw], racc);
            }
            rdsl[lw] = racc;
            xsl[lw] = xv;
        } else {
            // -------- waves 0-7: stream W_h slice (row-split matvec1) -----
            const int r = tid >> 3, l8 = tid & 7;   // 64 rows x 8 lanes
            const float4* Wr = (const float4*)(W_h + (size_t)(k * SLICE + r) * DIM);
            const float4* wk4 = (const float4*)work;
#pragma unroll 4
            for (int j = 0; j < 16; ++j) {
                int f = l8 + 8 * j;
                float4 w4 = Wr[f];
                float4 v4 = wk4[f];
                mv1 = fmaf(w4.x, v4.x, mv1);
                mv1 = fmaf(w4.y, v4.y, mv1);
                mv1 = fmaf(w4.z, v4.z, mv1);
                mv1 = fmaf(w4.w, v4.w, mv1);
            }
        }
        __syncthreads();  // JOIN1: rdsl/xsl ready, mv1 partials ready

        if (tid < 512) {
            const int r = tid >> 3, l8 = tid & 7;
            mv1 += __shfl_down(mv1, 4, 8);
            mv1 += __shfl_down(mv1, 2, 8);
            mv1 += __shfl_down(mv1, 1, 8);
            if (l8 == 0)
                wnsl[r] = tanhf(mv1 + xsl[r] + rdsl[r]);
        }
        __syncthreads();  // JOIN2: wnsl ready

        if (tid < 512) {
            // column-sliced matvec2: w_part[tid] over this WG's 64 columns,
            // coalesced via transposed Wwt.
            const float* Wc = Wwt + (size_t)(k * SLICE) * DIM + tid;
            float acc2 = 0.f;
#pragma unroll 8
            for (int c = 0; c < SLICE; ++c)
                acc2 = fmaf(Wc[(size_t)c * DIM], wnsl[c], acc2);
            __hip_atomic_store(&pb[k * DIM + tid], acc2, __ATOMIC_RELAXED,
                               SCOPE_AGENT);
        } else {
            // wave 8: publish the work_new slice
            const int lw = tid - 512;
            __hip_atomic_store(&wnb[k * SLICE + lw], wnsl[lw],
                               __ATOMIC_RELAXED, SCOPE_AGENT);
        }
        asm volatile("s_waitcnt vmcnt(0)" ::: "memory");
        __syncthreads();  // JOIN3: all publishes issued & drained

        if (tid == 512 && !deadflag) {
            __hip_atomic_fetch_add(cnt_b, 1, __ATOMIC_RELAXED, SCOPE_AGENT);
            const int target = (t + 1) * KSPLIT;
            int it = 0;
            while (__hip_atomic_load(cnt_b, __ATOMIC_RELAXED, SCOPE_AGENT) <
                   target) {
                if (++it > (1 << 20)) { deadflag = 1; break; }
                if (it > 8) __builtin_amdgcn_s_sleep(2);
            }
        }
        __syncthreads();  // JOIN4: exchange complete

        float wn_v = 0.f, wv_v = 0.f;
        if (tid < 512) {
            wn_v = __hip_atomic_load(&wnb[tid], __ATOMIC_RELAXED, SCOPE_AGENT);
            const float* pbase = pb + tid;
#pragma unroll
            for (int j = 0; j < KSPLIT; ++j)
                wv_v += __hip_atomic_load(pbase + j * DIM, __ATOMIC_RELAXED,
                                          SCOPE_AGENT);
            wvec[tid] = wv_v;
        }
        __syncthreads();  // JOIN5: wvec in LDS

        // write scores: 16 lanes/slot, slot-rotated (2-way banks, free)
        if (tid < 512) {
            const int s = tid >> 4, l16 = tid & 15;
            float p = 0.f;
#pragma unroll 4
            for (int j = 0; j < 32; ++j) {
                int idx = l16 + 16 * ((j + s) & 31);
                p = fmaf(tape[s][idx], wvec[idx], p);
            }
            p += __shfl_down(p, 8, 16);
            p += __shfl_down(p, 4, 16);
            p += __shfl_down(p, 2, 16);
            p += __shfl_down(p, 1, 16);
            if (l16 == 0) scores[s] = p * inv_sqrt_d;
        }
        __syncthreads();  // JOIN6: scores ready

        if (tid < 32) prob[tid] = entmax_wave(scores[tid], tid);  // beta
        __syncthreads();  // JOIN7: prob ready

        if (tid < 512) {
            // tape update (same expression as reference for bitwise parity
            // with round-2 accuracy), work swap, h_seq slice write
#pragma unroll
            for (int n = 0; n < NSLOTS; ++n) {
                float bb = prob[n];
                float tv = tape[n][tid];
                tape[n][tid] = tv * (1.0f - bb) + bb * wv_v;
            }
            work[tid] = wn_v;
            if ((tid >> 6) == k)
                hseq_b[(size_t)t * DIM + tid] = wn_v;
        }
        __syncthreads();  // JOIN8: tape/work consistent for next step
    }

    // epilogue: WG k writes tape slots [k*4,(k+1)*4) and its h_last slice
    const size_t tape_off = (size_t)BATCH * SEQT * DIM + (size_t)b * NSLOTS * DIM;
    for (int i = tid; i < 4 * DIM; i += TPB)
        out[tape_off + (size_t)k * 4 * DIM + i] = ((float*)tape)[k * 4 * DIM + i];
    if (tid < SLICE)
        out[(size_t)BATCH * SEQT * DIM + (size_t)BATCH * NSLOTS * DIM +
            (size_t)b * DIM + k * SLICE + tid] = work[k * SLICE + tid];
}

// ============================================================================
extern "C" void kernel_launch(void* const* d_in, const int* in_sizes, int n_in,
                              void* d_out, int out_size, void* d_ws,
                              size_t ws_size, hipStream_t stream)
{
    const float* x_seq   = (const float*)d_in[0];
    const float* h_tape  = (const float*)d_in[1];
    const float* h_work  = (const float*)d_in[2];
    const float* W_h     = (const float*)d_in[3];
    const float* W_x     = (const float*)d_in[4];
    const float* b_h     = (const float*)d_in[5];
    const float* W_write = (const float*)d_in[6];
    float* out = (float*)d_out;

    float* Wwt   = (float*)d_ws;                       // 512*512
    float* wn_x  = Wwt + DIM * DIM;                    // 2*32*512
    float* parts = wn_x + 2 * BATCH * DIM;             // 2*32*8*512
    int*   cnt   = (int*)(parts + 2 * BATCH * KSPLIT * DIM);  // 32*32

    hipMemsetAsync(cnt, 0, BATCH * 32 * sizeof(int), stream);

    dim3 gt(16, 16);
    transpose512_kernel<<<gt, dim3(32, 8), 0, stream>>>(W_write, Wwt);

    dim3 g1((BATCH * SEQT) / 64, DIM / 64);
    xw_gemm_kernel<<<g1, 256, 0, stream>>>(x_seq, W_x, b_h, out);

    recurrent_kernel<<<BATCH * KSPLIT, TPB, 0, stream>>>(
        h_tape, h_work, W_h, Wwt, out, wn_x, parts, cnt);
}